// Round 1
// baseline (264.144 us; speedup 1.0000x reference)
//
#include <hip/hip_runtime.h>
#include <math.h>

// Problem shape (fixed by reference): x [32,256,64,64] f32, W [1,2,7,7], b [1]
constexpr int B_  = 32;
constexpr int C_  = 256;
constexpr int H_  = 64;
constexpr int W_  = 64;
constexpr int HW_ = H_ * W_;              // 4096
constexpr size_t CHW_ = (size_t)C_ * HW_; // 1048576

// ---------------------------------------------------------------------------
// Kernel 1: channel-wise max + mean pool.
// One block per (b, h) row: 256 threads = 16 w-groups (4 cols each, float4)
// x 16 channel-groups (16 channels each). LDS combine across channel groups.
// ---------------------------------------------------------------------------
__global__ __launch_bounds__(256) void pool_kernel(const float* __restrict__ x,
                                                   float* __restrict__ pool) {
    const int blk = blockIdx.x;        // 0 .. B_*H_-1  (2048)
    const int b   = blk >> 6;
    const int h   = blk & 63;
    const int tid = threadIdx.x;
    const int wg  = tid & 15;          // w-group: columns wg*4 .. wg*4+3
    const int cg  = tid >> 4;          // channel group: channels cg*16 .. cg*16+15

    const float* base = x + (size_t)b * CHW_ + (size_t)(cg * 16) * HW_ + h * W_ + wg * 4;
    float4 v  = *(const float4*)base;
    float4 mx = v, sm = v;
#pragma unroll
    for (int c = 1; c < 16; ++c) {
        float4 u = *(const float4*)(base + (size_t)c * HW_);
        mx.x = fmaxf(mx.x, u.x); mx.y = fmaxf(mx.y, u.y);
        mx.z = fmaxf(mx.z, u.z); mx.w = fmaxf(mx.w, u.w);
        sm.x += u.x; sm.y += u.y; sm.z += u.z; sm.w += u.w;
    }

    __shared__ float4 lmax[16][16];    // [cg][wg]  8 KiB
    __shared__ float4 lsum[16][16];    // 8 KiB
    lmax[cg][wg] = mx;
    lsum[cg][wg] = sm;
    __syncthreads();

    if (tid < 16) {                    // one thread per w-group does the 16-way combine
        const int w = tid;
        float4 M = lmax[0][w], S = lsum[0][w];
#pragma unroll
        for (int g = 1; g < 16; ++g) {
            float4 m2 = lmax[g][w], s2 = lsum[g][w];
            M.x = fmaxf(M.x, m2.x); M.y = fmaxf(M.y, m2.y);
            M.z = fmaxf(M.z, m2.z); M.w = fmaxf(M.w, m2.w);
            S.x += s2.x; S.y += s2.y; S.z += s2.z; S.w += s2.w;
        }
        const float inv = 1.0f / 256.0f;
        float4 A = make_float4(S.x * inv, S.y * inv, S.z * inv, S.w * inv);
        // pool layout [B][2][H][W]: plane 0 = max, plane 1 = avg (concat order)
        float* pm = pool + (size_t)b * 2 * HW_ + h * W_ + w * 4;
        *(float4*)pm          = M;
        *(float4*)(pm + HW_)  = A;
    }
}

// ---------------------------------------------------------------------------
// Kernel 2: 7x7 conv (2ch -> 1ch, pad 3) + bias + sigmoid.
// Weights staged in LDS; pool map (1 MB) is L2-resident.
// ---------------------------------------------------------------------------
__global__ __launch_bounds__(256) void conv_kernel(const float* __restrict__ pool,
                                                   const float* __restrict__ Wp,
                                                   const float* __restrict__ bp,
                                                   float* __restrict__ samap) {
    __shared__ float sw[98];
    const int tid = threadIdx.x;
    if (tid < 98) sw[tid] = Wp[tid];
    __syncthreads();

    const int t  = blockIdx.x * 256 + tid;   // 0 .. 131071
    const int b  = t >> 12;
    const int hw = t & 4095;
    const int h  = hw >> 6;
    const int w  = hw & 63;

    const float* pb = pool + (size_t)b * 2 * HW_;
    float acc = bp[0];
#pragma unroll
    for (int i = 0; i < 2; ++i) {
        const float* pc = pb + i * HW_;
        const float* wc = sw + i * 49;
#pragma unroll
        for (int kh = 0; kh < 7; ++kh) {
            const int hh = h + kh - 3;
            if (hh < 0 || hh >= H_) continue;
#pragma unroll
            for (int kw = 0; kw < 7; ++kw) {
                const int ww = w + kw - 3;
                if (ww < 0 || ww >= W_) continue;
                acc = fmaf(pc[hh * W_ + ww], wc[kh * 7 + kw], acc);
            }
        }
    }
    samap[t] = 1.0f / (1.0f + expf(-acc));
}

// ---------------------------------------------------------------------------
// Kernel 3: out = x * samap (broadcast over channels), float4.
// ---------------------------------------------------------------------------
__global__ __launch_bounds__(256) void scale_kernel(const float* __restrict__ x,
                                                    const float* __restrict__ samap,
                                                    float* __restrict__ out) {
    const int t = blockIdx.x * 256 + threadIdx.x;  // 0 .. 8388607
    const size_t o = (size_t)t * 4;                // element offset
    const int b  = (int)(o >> 20);                 // / (C_*HW_)
    const int hw = (int)(o & 4095);
    float4 xv = *(const float4*)(x + o);
    float4 sv = *(const float4*)(samap + b * HW_ + hw);
    float4 ov = make_float4(xv.x * sv.x, xv.y * sv.y, xv.z * sv.z, xv.w * sv.w);
    *(float4*)(out + o) = ov;
}

extern "C" void kernel_launch(void* const* d_in, const int* in_sizes, int n_in,
                              void* d_out, int out_size, void* d_ws, size_t ws_size,
                              hipStream_t stream) {
    const float* x  = (const float*)d_in[0];
    const float* Wp = (const float*)d_in[1];
    const float* bp = (const float*)d_in[2];
    float* out = (float*)d_out;

    // workspace: pool [32][2][64][64] then samap [32][64][64]  (1.5 MB total)
    float* pool  = (float*)d_ws;
    float* samap = pool + (size_t)B_ * 2 * HW_;

    pool_kernel<<<B_ * H_, 256, 0, stream>>>(x, pool);
    conv_kernel<<<(B_ * HW_) / 256, 256, 0, stream>>>(pool, Wp, bp, samap);
    scale_kernel<<<(B_ * (int)CHW_) / (4 * 256), 256, 0, stream>>>(x, samap, out);
}

// Round 3
// 257.755 us; speedup vs baseline: 1.0248x; 1.0248x over previous
//
#include <hip/hip_runtime.h>
#include <math.h>

// Problem shape (fixed by reference): x [32,256,64,64] f32, W [1,2,7,7], b [1]
constexpr int B_  = 32;
constexpr int C_  = 256;
constexpr int H_  = 64;
constexpr int W_  = 64;
constexpr int HW_ = H_ * W_;              // 4096
constexpr size_t CHW_ = (size_t)C_ * HW_; // 1048576

typedef float v4f __attribute__((ext_vector_type(4)));  // native vec for nontemporal store

// ---------------------------------------------------------------------------
// Kernel 1: channel-wise max + mean pool.
// One block per (b, h) row: 256 threads = 16 w-groups (4 cols each, float4)
// x 16 channel-groups (16 channels each). LDS combine across channel groups.
// ---------------------------------------------------------------------------
__global__ __launch_bounds__(256) void pool_kernel(const float* __restrict__ x,
                                                   float* __restrict__ pool) {
    const int blk = blockIdx.x;        // 0 .. B_*H_-1  (2048)
    const int b   = blk >> 6;
    const int h   = blk & 63;
    const int tid = threadIdx.x;
    const int wg  = tid & 15;          // w-group: columns wg*4 .. wg*4+3
    const int cg  = tid >> 4;          // channel group: channels cg*16 .. cg*16+15

    const float* base = x + (size_t)b * CHW_ + (size_t)(cg * 16) * HW_ + h * W_ + wg * 4;
    float4 v  = *(const float4*)base;
    float4 mx = v, sm = v;
#pragma unroll
    for (int c = 1; c < 16; ++c) {
        float4 u = *(const float4*)(base + (size_t)c * HW_);
        mx.x = fmaxf(mx.x, u.x); mx.y = fmaxf(mx.y, u.y);
        mx.z = fmaxf(mx.z, u.z); mx.w = fmaxf(mx.w, u.w);
        sm.x += u.x; sm.y += u.y; sm.z += u.z; sm.w += u.w;
    }

    __shared__ float4 lmax[16][16];    // [cg][wg]  8 KiB
    __shared__ float4 lsum[16][16];    // 8 KiB
    lmax[cg][wg] = mx;
    lsum[cg][wg] = sm;
    __syncthreads();

    if (tid < 16) {                    // one thread per w-group does the 16-way combine
        const int w = tid;
        float4 M = lmax[0][w], S = lsum[0][w];
#pragma unroll
        for (int g = 1; g < 16; ++g) {
            float4 m2 = lmax[g][w], s2 = lsum[g][w];
            M.x = fmaxf(M.x, m2.x); M.y = fmaxf(M.y, m2.y);
            M.z = fmaxf(M.z, m2.z); M.w = fmaxf(M.w, m2.w);
            S.x += s2.x; S.y += s2.y; S.z += s2.z; S.w += s2.w;
        }
        const float inv = 1.0f / 256.0f;
        float4 A = make_float4(S.x * inv, S.y * inv, S.z * inv, S.w * inv);
        // pool layout [B][2][H][W]: plane 0 = max, plane 1 = avg (concat order)
        float* pm = pool + (size_t)b * 2 * HW_ + h * W_ + w * 4;
        *(float4*)pm          = M;
        *(float4*)(pm + HW_)  = A;
    }
}

// ---------------------------------------------------------------------------
// Kernel 2 (fused): 7x7 conv + bias + sigmoid for one (b,h) row, then scale
// all 256 channels of that row.  Block per (b,h): 2048 blocks, 256 threads.
// Pool halo (2 planes x 7 rows x 64 cols) staged in LDS; samap row in LDS.
// out stores are nontemporal (streaming, never re-read) to preserve x in L2/L3.
// ---------------------------------------------------------------------------
__global__ __launch_bounds__(256) void conv_scale_kernel(const float* __restrict__ x,
                                                         const float* __restrict__ pool,
                                                         const float* __restrict__ Wp,
                                                         const float* __restrict__ bp,
                                                         float* __restrict__ out) {
    const int blk = blockIdx.x;        // b*64 + h
    const int b   = blk >> 6;
    const int h   = blk & 63;
    const int tid = threadIdx.x;

    __shared__ float sw[98];
    __shared__ float spool[2][7][64];  // zero-padded halo rows
    __shared__ float ssa[64];          // sigmoid(conv) for this row

    if (tid < 98) sw[tid] = Wp[tid];
#pragma unroll
    for (int idx = tid; idx < 896; idx += 256) {
        const int plane = idx / 448;
        const int rem   = idx - plane * 448;
        const int r     = rem >> 6;
        const int w     = rem & 63;
        const int hh    = h + r - 3;
        spool[plane][r][w] = (hh >= 0 && hh < H_)
            ? pool[((size_t)b * 2 + plane) * HW_ + hh * W_ + w] : 0.0f;
    }
    __syncthreads();

    if (tid < 64) {
        float acc = bp[0];
#pragma unroll
        for (int p = 0; p < 2; ++p) {
            const float* wc = sw + p * 49;
#pragma unroll
            for (int kh = 0; kh < 7; ++kh) {
#pragma unroll
                for (int kw = 0; kw < 7; ++kw) {
                    const int ww = tid + kw - 3;
                    if (ww >= 0 && ww < W_)
                        acc = fmaf(spool[p][kh][ww], wc[kh * 7 + kw], acc);
                }
            }
        }
        ssa[tid] = 1.0f / (1.0f + expf(-acc));
    }
    __syncthreads();

    // Scale phase: 256 threads = 16 w-groups (float4) x 16 channel-base.
    const int wq = tid & 15;           // columns wq*4 .. wq*4+3
    const int c0 = tid >> 4;           // channels c0, c0+16, ..., c0+240
    const float4 sv = *(const float4*)&ssa[wq * 4];
    const size_t base = (size_t)b * CHW_ + (size_t)c0 * HW_ + h * W_ + wq * 4;
    const float* xb = x + base;
    float*       ob = out + base;
#pragma unroll
    for (int j = 0; j < 16; ++j) {
        const float4 xv = *(const float4*)(xb + (size_t)j * 16 * HW_);
        v4f ov;
        ov.x = xv.x * sv.x; ov.y = xv.y * sv.y;
        ov.z = xv.z * sv.z; ov.w = xv.w * sv.w;
        __builtin_nontemporal_store(ov, (v4f*)(ob + (size_t)j * 16 * HW_));
    }
}

extern "C" void kernel_launch(void* const* d_in, const int* in_sizes, int n_in,
                              void* d_out, int out_size, void* d_ws, size_t ws_size,
                              hipStream_t stream) {
    const float* x  = (const float*)d_in[0];
    const float* Wp = (const float*)d_in[1];
    const float* bp = (const float*)d_in[2];
    float* out = (float*)d_out;

    // workspace: pool [32][2][64][64]  (1 MB)
    float* pool = (float*)d_ws;

    pool_kernel<<<B_ * H_, 256, 0, stream>>>(x, pool);
    conv_scale_kernel<<<B_ * H_, 256, 0, stream>>>(x, pool, Wp, bp, out);
}